// Round 2
// baseline (320.969 us; speedup 1.0000x reference)
//
#include <hip/hip_runtime.h>
#include <math.h>
#include <limits.h>

#define B_  8
#define L_  128
#define VF_ 32128
#define V_  32100
#define D_  768

#define SEGS_ 2
#define NV4_  (VF_ / 4)   // 8032 float4s per row
#define HALF_ (NV4_ / 2)  // 4016 float4s per half-row

typedef unsigned long long u64;

// Monotone map: f1 > f2  <=>  fmap(f1) > fmap(f2)  (inputs have no NaNs)
__device__ __forceinline__ unsigned int fmap(float f) {
    unsigned int u = __float_as_uint(f);
    return (u & 0x80000000u) ? ~u : (u | 0x80000000u);
}

// ---------------------------------------------------------------------------
// Kernel 1: segment argmax of logits+gumbel, streaming-loop shape (m13-like).
// Grid = 1024 rows x 2 halves = 2048 blocks (8/CU), 256 threads,
// __launch_bounds__(256,8) -> 32 waves/CU residency target.
// Each thread: 16-iteration strided loop over its half-row (unroll 4 keeps
// ~8 float4 loads rotating in flight). Indices clamped to row end; half-0's
// 16th iteration overlaps into half-1's range -- both harmless: keys carry
// GLOBAL indices, so duplicated candidates merge identically under max.
// Per-block result -> plain store keys[row*2+half] (no atomics, no memset).
// ---------------------------------------------------------------------------
__global__ __launch_bounds__(256, 8) void k_argmax(
    const float* __restrict__ logits, const float* __restrict__ gumbel,
    u64* __restrict__ keys)
{
    const int row  = blockIdx.x >> 1;           // 0..1023
    const int half = blockIdx.x & 1;            // 0..1
    const int tid  = threadIdx.x;               // 0..255
    const size_t rowoff = (size_t)row * VF_;
    const float4* lp = (const float4*)(logits + rowoff);
    const float4* gp = (const float4*)(gumbel + rowoff);

    float bv = -INFINITY;
    int   bi = 0;
    int   i  = half * HALF_ + tid;
    #pragma unroll 4
    for (int it = 0; it < 16; ++it) {
        const int ii = (i < NV4_ - 1) ? i : (NV4_ - 1);
        const float4 a = lp[ii];
        const float4 g = gp[ii];
        float v;
        v = a.x + g.x; if (v > bv) { bv = v; bi = 4*ii + 0; }
        v = a.y + g.y; if (v > bv) { bv = v; bi = 4*ii + 1; }
        v = a.z + g.z; if (v > bv) { bv = v; bi = 4*ii + 2; }
        v = a.w + g.w; if (v > bv) { bv = v; bi = 4*ii + 3; }
        i += 256;
    }

    // bigger value wins; equal value -> smaller idx (larger VF-idx) wins
    u64 k = ((u64)fmap(bv) << 32) | (u64)(VF_ - bi);
    for (int off = 32; off > 0; off >>= 1) {
        u64 o = __shfl_down(k, off, 64);
        if (o > k) k = o;
    }
    __shared__ u64 s_k[4];
    if ((tid & 63) == 0) s_k[tid >> 6] = k;
    __syncthreads();
    if (tid == 0) {
        u64 kk = s_k[0];
        if (s_k[1] > kk) kk = s_k[1];
        if (s_k[2] > kk) kk = s_k[2];
        if (s_k[3] > kk) kk = s_k[3];
        keys[blockIdx.x] = kk;
    }
}

// ---------------------------------------------------------------------------
// Kernel 2 (fused): per-(b,l) block. Merges the row's 2 segment keys,
// redundantly recomputes the per-b control logic (cheap: 256 int loads),
// then gathers the W row(s) into the output. 192 threads (768 floats / f4).
// ---------------------------------------------------------------------------
__global__ __launch_bounds__(192) void k_emb(
    const float* __restrict__ W,
    const int* __restrict__ rwrt, const int* __restrict__ psg,
    const u64* __restrict__ keys,
    float* __restrict__ out, float* __restrict__ nn_out)
{
    const int row = blockIdx.x;          // b*128 + l
    const int b = row >> 7;
    const int l = row & 127;
    const int t = threadIdx.x;           // 0..191

    __shared__ int s_att[L_];
    __shared__ int s_extr[L_];
    __shared__ u64 s_keys[SEGS_];
    __shared__ int s_len, s_first, s_rA, s_rB;

    if (t == 0) s_first = INT_MAX;
    if (t < L_) s_att[t] = rwrt[b * L_ + t];
    if (t >= 128 && t < 128 + SEGS_) s_keys[t - 128] = keys[row * SEGS_ + (t - 128)];
    __syncthreads();

    if (t == 0) {
        int len = 0;
        for (int i = 0; i < L_; ++i) len += (s_att[i] == 1);
        s_len = len;
    }
    if (t < L_) s_extr[t] = (1 - s_att[L_ - 1 - t]) * psg[b * L_ + t];
    __syncthreads();

    if (t < L_) {
        int src = (t - s_len + L_) & (L_ - 1);
        if (s_extr[src] != 0) atomicMin(&s_first, t);
    }
    __syncthreads();

    if (t == 0) {
        u64 kk = s_keys[0];
        #pragma unroll
        for (int i = 1; i < SEGS_; ++i) if (s_keys[i] > kk) kk = s_keys[i];
        const int am   = VF_ - (int)(kk & 0xFFFFFFFFull);
        const int srcl = (l - s_len + L_) & (L_ - 1);
        const int idxv = s_extr[srcl];
        const int flag = (l >= s_first) ? 1 : 0;
        const int rA = (s_att[l] == 1 && am < V_) ? am : -1;
        const int rB = flag ? idxv : -1;
        s_rA = rA; s_rB = rB;
        // Every realized row is exactly one W row (or zero): nn = its index.
        // Zero row -> all-zero sims -> jnp.argmax ties to 0.
        const int nn = (rA >= 0) ? rA : ((rB >= 0) ? rB : 0);
        nn_out[row] = (float)nn;
    }
    __syncthreads();

    const int rA = s_rA;
    const int rB = s_rB;
    float4 v = make_float4(0.f, 0.f, 0.f, 0.f);
    if (rA >= 0) {
        float4 a = ((const float4*)(W + (size_t)rA * D_))[t];
        v.x += a.x; v.y += a.y; v.z += a.z; v.w += a.w;
    }
    if (rB >= 0) {
        float4 a = ((const float4*)(W + (size_t)rB * D_))[t];
        v.x += a.x; v.y += a.y; v.z += a.z; v.w += a.w;
    }
    ((float4*)(out + (size_t)row * D_))[t] = v;
}

extern "C" void kernel_launch(void* const* d_in, const int* in_sizes, int n_in,
                              void* d_out, int out_size, void* d_ws, size_t ws_size,
                              hipStream_t stream)
{
    const float* logits = (const float*)d_in[0];
    const float* gumbel = (const float*)d_in[1];
    const float* W      = (const float*)d_in[2];
    const int*   rwrt   = (const int*)d_in[3];
    const int*   psg    = (const int*)d_in[4];

    float* out    = (float*)d_out;                       // embeds: 8*128*768
    float* nn_out = out + (size_t)B_ * L_ * D_;          // nn_idx as float: 1024

    u64* keys = (u64*)d_ws;                  // 2048 u64 segment keys (16 KB)

    k_argmax<<<B_ * L_ * SEGS_, 256, 0, stream>>>(logits, gumbel, keys);
    k_emb<<<B_ * L_, 192, 0, stream>>>(W, rwrt, psg, keys, out, nn_out);
}

// Round 3
// 309.761 us; speedup vs baseline: 1.0362x; 1.0362x over previous
//
#include <hip/hip_runtime.h>
#include <math.h>
#include <limits.h>

#define B_  8
#define L_  128
#define VF_ 32128
#define V_  32100
#define D_  768

#define SEGS_ 2
#define NV4_  (VF_ / 4)   // 8032 float4s per row
#define HALF_ (NV4_ / 2)  // 4016 float4s per half-row

typedef unsigned long long u64;
typedef float f4v __attribute__((ext_vector_type(4)));

// Monotone map: f1 > f2  <=>  fmap(f1) > fmap(f2)  (inputs have no NaNs)
__device__ __forceinline__ unsigned int fmap(float f) {
    unsigned int u = __float_as_uint(f);
    return (u & 0x80000000u) ? ~u : (u | 0x80000000u);
}

// ---------------------------------------------------------------------------
// Kernel 1: segment argmax of logits+gumbel, streaming-loop shape.
// Grid = 1024 rows x 2 halves = 2048 blocks (8/CU), 256 threads, (256,8).
// CACHE POLICY (round-3 single-variable change): gumbel is loaded with
// __builtin_nontemporal_load (MUBUF `nt` -> no L2/L3 allocate). The
// combined 263 MB working set thrashes the 256 MB L3 (50% steady-state
// miss, FETCH_SIZE==131MB). With gumbel non-allocating, the allocating
// working set is logits alone (131 MB) -> fits L3 -> no thrash; gumbel
// streams from HBM in parallel. Indices clamped to row end; keys carry
// GLOBAL indices so duplicated candidates merge identically under max.
// ---------------------------------------------------------------------------
__global__ __launch_bounds__(256, 8) void k_argmax(
    const float* __restrict__ logits, const float* __restrict__ gumbel,
    u64* __restrict__ keys)
{
    const int row  = blockIdx.x >> 1;           // 0..1023
    const int half = blockIdx.x & 1;            // 0..1
    const int tid  = threadIdx.x;               // 0..255
    const size_t rowoff = (size_t)row * VF_;
    const f4v* lp = (const f4v*)(logits + rowoff);
    const f4v* gp = (const f4v*)(gumbel + rowoff);

    float bv = -INFINITY;
    int   bi = 0;
    int   i  = half * HALF_ + tid;
    #pragma unroll 4
    for (int it = 0; it < 16; ++it) {
        const int ii = (i < NV4_ - 1) ? i : (NV4_ - 1);
        const f4v a = lp[ii];
        const f4v g = __builtin_nontemporal_load(gp + ii);
        float v;
        v = a[0] + g[0]; if (v > bv) { bv = v; bi = 4*ii + 0; }
        v = a[1] + g[1]; if (v > bv) { bv = v; bi = 4*ii + 1; }
        v = a[2] + g[2]; if (v > bv) { bv = v; bi = 4*ii + 2; }
        v = a[3] + g[3]; if (v > bv) { bv = v; bi = 4*ii + 3; }
        i += 256;
    }

    // bigger value wins; equal value -> smaller idx (larger VF-idx) wins
    u64 k = ((u64)fmap(bv) << 32) | (u64)(VF_ - bi);
    for (int off = 32; off > 0; off >>= 1) {
        u64 o = __shfl_down(k, off, 64);
        if (o > k) k = o;
    }
    __shared__ u64 s_k[4];
    if ((tid & 63) == 0) s_k[tid >> 6] = k;
    __syncthreads();
    if (tid == 0) {
        u64 kk = s_k[0];
        if (s_k[1] > kk) kk = s_k[1];
        if (s_k[2] > kk) kk = s_k[2];
        if (s_k[3] > kk) kk = s_k[3];
        keys[blockIdx.x] = kk;
    }
}

// ---------------------------------------------------------------------------
// Kernel 2 (fused): per-(b,l) block. Merges the row's 2 segment keys,
// redundantly recomputes the per-b control logic (cheap: 256 int loads),
// then gathers the W row(s) into the output. 192 threads (768 floats / f4).
// ---------------------------------------------------------------------------
__global__ __launch_bounds__(192) void k_emb(
    const float* __restrict__ W,
    const int* __restrict__ rwrt, const int* __restrict__ psg,
    const u64* __restrict__ keys,
    float* __restrict__ out, float* __restrict__ nn_out)
{
    const int row = blockIdx.x;          // b*128 + l
    const int b = row >> 7;
    const int l = row & 127;
    const int t = threadIdx.x;           // 0..191

    __shared__ int s_att[L_];
    __shared__ int s_extr[L_];
    __shared__ u64 s_keys[SEGS_];
    __shared__ int s_len, s_first, s_rA, s_rB;

    if (t == 0) s_first = INT_MAX;
    if (t < L_) s_att[t] = rwrt[b * L_ + t];
    if (t >= 128 && t < 128 + SEGS_) s_keys[t - 128] = keys[row * SEGS_ + (t - 128)];
    __syncthreads();

    if (t == 0) {
        int len = 0;
        for (int i = 0; i < L_; ++i) len += (s_att[i] == 1);
        s_len = len;
    }
    if (t < L_) s_extr[t] = (1 - s_att[L_ - 1 - t]) * psg[b * L_ + t];
    __syncthreads();

    if (t < L_) {
        int src = (t - s_len + L_) & (L_ - 1);
        if (s_extr[src] != 0) atomicMin(&s_first, t);
    }
    __syncthreads();

    if (t == 0) {
        u64 kk = s_keys[0];
        #pragma unroll
        for (int i = 1; i < SEGS_; ++i) if (s_keys[i] > kk) kk = s_keys[i];
        const int am   = VF_ - (int)(kk & 0xFFFFFFFFull);
        const int srcl = (l - s_len + L_) & (L_ - 1);
        const int idxv = s_extr[srcl];
        const int flag = (l >= s_first) ? 1 : 0;
        const int rA = (s_att[l] == 1 && am < V_) ? am : -1;
        const int rB = flag ? idxv : -1;
        s_rA = rA; s_rB = rB;
        // Every realized row is exactly one W row (or zero): nn = its index.
        // Zero row -> all-zero sims -> jnp.argmax ties to 0.
        const int nn = (rA >= 0) ? rA : ((rB >= 0) ? rB : 0);
        nn_out[row] = (float)nn;
    }
    __syncthreads();

    const int rA = s_rA;
    const int rB = s_rB;
    float4 v = make_float4(0.f, 0.f, 0.f, 0.f);
    if (rA >= 0) {
        float4 a = ((const float4*)(W + (size_t)rA * D_))[t];
        v.x += a.x; v.y += a.y; v.z += a.z; v.w += a.w;
    }
    if (rB >= 0) {
        float4 a = ((const float4*)(W + (size_t)rB * D_))[t];
        v.x += a.x; v.y += a.y; v.z += a.z; v.w += a.w;
    }
    ((float4*)(out + (size_t)row * D_))[t] = v;
}

extern "C" void kernel_launch(void* const* d_in, const int* in_sizes, int n_in,
                              void* d_out, int out_size, void* d_ws, size_t ws_size,
                              hipStream_t stream)
{
    const float* logits = (const float*)d_in[0];
    const float* gumbel = (const float*)d_in[1];
    const float* W      = (const float*)d_in[2];
    const int*   rwrt   = (const int*)d_in[3];
    const int*   psg    = (const int*)d_in[4];

    float* out    = (float*)d_out;                       // embeds: 8*128*768
    float* nn_out = out + (size_t)B_ * L_ * D_;          // nn_idx as float: 1024

    u64* keys = (u64*)d_ws;                  // 2048 u64 segment keys (16 KB)

    k_argmax<<<B_ * L_ * SEGS_, 256, 0, stream>>>(logits, gumbel, keys);
    k_emb<<<B_ * L_, 192, 0, stream>>>(W, rwrt, psg, keys, out, nn_out);
}